// Round 15
// baseline (1600.722 us; speedup 1.0000x reference)
//
#include <hip/hip_runtime.h>
#include <hip/hip_fp16.h>
#include <stdint.h>

#define IN_F   4096
#define OUT_F  11008
#define TOKENS 2048
#define BM 128
#define BN 128
#define BK2 128            // i8 path K-tile == group size
#define NT2 (IN_F / BK2)   // 32 tiles
#define NGROUP 32
#define OPW (OUT_F / 8)

typedef _Float16 f16;
typedef __attribute__((ext_vector_type(2))) _Float16 f16x2;
typedef __attribute__((ext_vector_type(8))) _Float16 f16x8;
typedef __attribute__((ext_vector_type(4))) float f32x4;
typedef __attribute__((ext_vector_type(4))) int   i32x4;

typedef __attribute__((address_space(3))) uint32_t lds_u32_t;
typedef const __attribute__((address_space(1))) uint32_t glb_u32_t;

#define SB0() __builtin_amdgcn_sched_barrier(0)

static __device__ __forceinline__ void gload_lds16(const void* g, void* l) {
    __builtin_amdgcn_global_load_lds((glb_u32_t*)g, (lds_u32_t*)l, 16, 0, 0);
}

// ---------------- pre-pass: per-row i8 quantization of x ----------------
// xi byte order per 16-elem unit: {0,2,4,6, 1,3,5,7, 8,10,12,14, 9,11,13,15}
// (mirrors the nibble-unpack order of qweight words on the B side)
__global__ __launch_bounds__(256) void quant_x_kernel(const float* __restrict__ x,
                                                      char* __restrict__ xi,
                                                      float* __restrict__ aws) {
    __shared__ float red[4];
    const int row = blockIdx.x;
    const int tid = threadIdx.x;
    const float* xr = x + (size_t)row * IN_F + tid * 16;
    float v[16];
    #pragma unroll
    for (int p = 0; p < 4; ++p) {
        const float4 t = *reinterpret_cast<const float4*>(xr + p * 4);
        v[p * 4 + 0] = t.x; v[p * 4 + 1] = t.y; v[p * 4 + 2] = t.z; v[p * 4 + 3] = t.w;
    }
    float m = 0.f;
    #pragma unroll
    for (int p = 0; p < 16; ++p) m = fmaxf(m, fabsf(v[p]));
    #pragma unroll
    for (int off = 32; off > 0; off >>= 1) m = fmaxf(m, __shfl_xor(m, off));
    if ((tid & 63) == 0) red[tid >> 6] = m;
    __syncthreads();
    m = fmaxf(fmaxf(red[0], red[1]), fmaxf(red[2], red[3]));
    const float a   = m * (1.0f / 127.0f);
    const float inv = (m > 0.f) ? 127.0f / m : 0.f;
    if (tid == 0) aws[row] = a;
    const float MAGIC = 12582912.0f;   // 1.5*2^23: RNE int in low byte
    uint32_t b[16];
    #pragma unroll
    for (int p = 0; p < 16; ++p)
        b[p] = __builtin_bit_cast(uint32_t, fmaf(v[p], inv, MAGIC)) & 0xFFu;
    i32x4 d;
    d[0] = (int)(b[0] | (b[2] << 8) | (b[4]  << 16) | (b[6]  << 24));
    d[1] = (int)(b[1] | (b[3] << 8) | (b[5]  << 16) | (b[7]  << 24));
    d[2] = (int)(b[8] | (b[10] << 8) | (b[12] << 16) | (b[14] << 24));
    d[3] = (int)(b[9] | (b[11] << 8) | (b[13] << 16) | (b[15] << 24));
    *reinterpret_cast<i32x4*>(xi + (size_t)row * IN_F + tid * 16) = d;
}

// ---------------- i8 GEMM: xi[2048][4096] x Wint -> f32 ----------------
__global__ __launch_bounds__(512, 4) void qgemm_i8_kernel(
    const char*     __restrict__ xi,
    const float*    __restrict__ aws,
    const uint32_t* __restrict__ qweight,
    const uint32_t* __restrict__ qzeros,
    const int*      __restrict__ qscales,
    const float*    __restrict__ qscales_zeros,
    const float*    __restrict__ qscales_scales,
    float*          __restrict__ out)
{
    // A,B i8 [128][128]; 16B unit (row, slot) holds k-unit slot^(row&7) -> conflict-free
    __shared__ __align__(16) char Ash[2][BM * BK2];   // 2 x 16 KiB
    __shared__ __align__(16) char Bsh[2][BN * BK2];   // 2 x 16 KiB (64 KiB total)

    const int tid  = threadIdx.x;
    const int lane = tid & 63;
    const int wid  = tid >> 6;
    const int kg   = wid >> 2;        // k-half (0: units 0-3, 1: units 4-7)
    const int wm   = (wid >> 1) & 1;
    const int wn   = wid & 1;

    const int mt = blockIdx.x & 15;
    const int nt = blockIdx.x >> 4;
    const int m0 = mt * BM;
    const int n0 = nt * BN;

    // ---- B staging: thread owns col colb, units {q, q+4}; 4 packed words/tile
    const int colb = tid & 127;
    const int q    = tid >> 7;        // 0..3
    const int ncol = n0 + colb;
    const int boff0 = colb * BK2 + ((q)     ^ (colb & 7)) * 16;
    const int boff1 = colb * BK2 + ((q + 4) ^ (colb & 7)) * 16;
    const uint32_t* bptr = qweight + (size_t)(2 * q) * OUT_F + ncol;

    // ---- A staging: 2 chunks/thread, linear dest, swizzled source
    const int arow0 = tid >> 3, aslot0 = tid & 7;
    const int arow1 = (tid + 512) >> 3, aslot1 = (tid + 512) & 7;
    const char* asrc0 = xi + (size_t)(m0 + arow0) * IN_F + (aslot0 ^ (arow0 & 7)) * 16;
    const char* asrc1 = xi + (size_t)(m0 + arow1) * IN_F + (aslot1 ^ (arow1 & 7)) * 16;
    const int adst0 = tid * 16, adst1 = (tid + 512) * 16;

    // ---- fragment offsets (this wave's 64-k half)
    const int lr = lane & 15;
    const int lo = lane >> 4;
    const int ku = kg * 4 + lo;       // k-unit 0..7
    int aoffr[4], boffr[4], cread[4];
    #pragma unroll
    for (int f = 0; f < 4; ++f) {
        const int ra = wm * 64 + f * 16 + lr;
        aoffr[f] = ra * BK2 + (ku ^ (ra & 7)) * 16;
        const int rb = wn * 64 + f * 16 + lr;
        boffr[f] = rb * BK2 + (ku ^ (rb & 7)) * 16;
        cread[f] = n0 + wn * 64 + f * 16 + lr;   // flush column of frag f
    }
    float qszr[4], qssr[4];
    #pragma unroll
    for (int f = 0; f < 4; ++f) {
        qszr[f] = qscales_zeros[cread[f]];
        qssr[f] = qscales_scales[cread[f]];
    }

    f32x4 acc[4][4];
    #pragma unroll
    for (int i = 0; i < 4; ++i)
        #pragma unroll
        for (int j = 0; j < 4; ++j) {
            f32x4 z = {0.f, 0.f, 0.f, 0.f};
            acc[i][j] = z;
        }

    auto load_bw = [&](int t_, uint32_t* w) {
        const uint32_t* p = bptr + (size_t)t_ * 16 * OUT_F;
        w[0] = p[0];
        w[1] = p[OUT_F];
        w[2] = p[(size_t)8 * OUT_F];
        w[3] = p[(size_t)9 * OUT_F];
    };
    auto mk_kz = [&](uint32_t zw_) -> uint32_t {
        const uint32_t znib = (zw_ >> ((ncol & 7) * 4)) & 0xFu;
        return (127u - znib) * 0x01010101u;   // per-byte: +(128-(z+1)), then ^0x80
    };
    auto unpack16 = [&](uint32_t wa, uint32_t wb, uint32_t kz) -> i32x4 {
        i32x4 d;
        d[0] = (int)(((( wa       ) & 0x0F0F0F0Fu) + kz) ^ 0x80808080u);
        d[1] = (int)((((wa >> 4)   & 0x0F0F0F0Fu) + kz) ^ 0x80808080u);
        d[2] = (int)(((( wb       ) & 0x0F0F0F0Fu) + kz) ^ 0x80808080u);
        d[3] = (int)((((wb >> 4)   & 0x0F0F0F0Fu) + kz) ^ 0x80808080u);
        return d;
    };
    auto stage_B = [&](int buf, const uint32_t* w, uint32_t kz) {
        *reinterpret_cast<i32x4*>(&Bsh[buf][boff0]) = unpack16(w[0], w[1], kz);
        *reinterpret_cast<i32x4*>(&Bsh[buf][boff1]) = unpack16(w[2], w[3], kz);
    };
    auto stage_A = [&](int buf, int t_) {
        gload_lds16(asrc0 + (size_t)t_ * BK2, &Ash[buf][adst0]);
        gload_lds16(asrc1 + (size_t)t_ * BK2, &Ash[buf][adst1]);
    };
    auto compute = [&](int buf, const float* sc) {
        i32x4 bf[4];
        #pragma unroll
        for (int f = 0; f < 4; ++f)
            bf[f] = *reinterpret_cast<const i32x4*>(&Bsh[buf][boffr[f]]);
        __builtin_amdgcn_s_setprio(1);
        #pragma unroll
        for (int i = 0; i < 4; ++i) {
            const i32x4 af = *reinterpret_cast<const i32x4*>(&Ash[buf][aoffr[i]]);
            #pragma unroll
            for (int j = 0; j < 4; ++j) {
                i32x4 zz = {0, 0, 0, 0};
                const i32x4 D = __builtin_amdgcn_mfma_i32_16x16x64_i8(af, bf[j], zz, 0, 0, 0);
                acc[i][j].x += sc[j] * (float)D[0];
                acc[i][j].y += sc[j] * (float)D[1];
                acc[i][j].z += sc[j] * (float)D[2];
                acc[i][j].w += sc[j] * (float)D[3];
            }
        }
        __builtin_amdgcn_s_setprio(0);
    };

    uint32_t wE[4], wO[4];
    uint32_t zwE, zwO;
    int swE[4], swO[4];

    // -------- prologue: stage tile 0; prime words(1)/zw(1)/sw(group 0) --------
    {
        uint32_t w0[4];
        load_bw(0, w0);
        const uint32_t kz0 = mk_kz(qzeros[ncol >> 3]);   // group 0
        stage_A(0, 0);
        stage_B(0, w0, kz0);
        load_bw(1, wE);
        zwE = qzeros[OPW + (ncol >> 3)];                 // group 1
        #pragma unroll
        for (int j = 0; j < 4; ++j) swE[j] = qscales[cread[j]];   // group 0 (flush t0)
        asm volatile("s_waitcnt vmcnt(0)" ::: "memory");
        asm volatile("s_waitcnt lgkmcnt(0)" ::: "memory");
        __builtin_amdgcn_s_barrier();
    }

// body: compute tile T (buf C) with scales from SC (group T); stage tile T+1
// into buf C^1 using WC (words T+1) + ZC (zeros group T+1); prefetch
// [bw(T+2), zw(T+2), sw(T+1)] into WL/ZL/SL. vmcnt(9) retires the 2 A-gloads.
#define BODY(C, T, WC, ZC, SC, WL, ZL, SL)                                        \
  {                                                                               \
    const int tn1_ = ((T) + 1 < NT2) ? (T) + 1 : NT2 - 1;                         \
    const int tn2_ = ((T) + 2 < NT2) ? (T) + 2 : NT2 - 1;                         \
    float scur_[4];                                                               \
    _Pragma("unroll") for (int j = 0; j < 4; ++j)                                 \
      scur_[j] = ((float)SC[j] - qszr[j]) * qssr[j];                              \
    const uint32_t kz_ = mk_kz(ZC);                                               \
    stage_B((C) ^ 1, WC, kz_);                                                    \
    stage_A((C) ^ 1, tn1_);                                                       \
    SB0();                                                                        \
    load_bw(tn2_, WL);                                                            \
    ZL = qzeros[(size_t)tn2_ * OPW + (ncol >> 3)];                                \
    _Pragma("unroll") for (int j = 0; j < 4; ++j)                                 \
      SL[j] = qscales[(size_t)tn1_ * OUT_F + cread[j]];                           \
    SB0();                                                                        \
    compute(C, scur_);                                                            \
    asm volatile("s_waitcnt vmcnt(9)" ::: "memory");                              \
    asm volatile("s_waitcnt lgkmcnt(0)" ::: "memory");                            \
    __builtin_amdgcn_s_barrier();                                                 \
  }

    for (int t = 0; t < NT2; t += 2) {
        BODY(0, t,     wE, zwE, swE, wO, zwO, swO)
        BODY(1, t + 1, wO, zwO, swO, wE, zwE, swE)
    }
#undef BODY

    // -------- cross-k-group reduction (2 rounds over Ash) --------
    __syncthreads();
    f32x4* scratch = reinterpret_cast<f32x4*>(&Ash[0][0]);   // 2048 f32x4
    const int wpos = wid & 3;
    #pragma unroll
    for (int qh = 0; qh < 2; ++qh) {
        if (kg == 1) {
            #pragma unroll
            for (int di = 0; di < 2; ++di)
                #pragma unroll
                for (int j = 0; j < 4; ++j)
                    scratch[wpos * 512 + (di * 4 + j) * 64 + lane] = acc[2 * qh + di][j];
        }
        __syncthreads();
        if (kg == 0) {
            #pragma unroll
            for (int di = 0; di < 2; ++di)
                #pragma unroll
                for (int j = 0; j < 4; ++j) {
                    const f32x4 p = scratch[wpos * 512 + (di * 4 + j) * 64 + lane];
                    acc[2 * qh + di][j].x += p.x; acc[2 * qh + di][j].y += p.y;
                    acc[2 * qh + di][j].z += p.z; acc[2 * qh + di][j].w += p.w;
                }
        }
        __syncthreads();
    }

    // -------- epilogue: C/D col=lane&15, row=(lane>>4)*4+reg; apply a[m] --------
    if (kg == 0) {
        const int orow = m0 + wm * 64 + lo * 4;
        const int ocol = n0 + wn * 64 + lr;
        #pragma unroll
        for (int i = 0; i < 4; ++i)
            #pragma unroll
            for (int j = 0; j < 4; ++j)
                #pragma unroll
                for (int r = 0; r < 4; ++r) {
                    const int rr = orow + i * 16 + r;
                    out[(size_t)rr * OUT_F + ocol + j * 16] = aws[rr] * acc[i][j][r];
                }
    }
}

// ---------------- fallback (no workspace): r10 f16 kernel, non-WS path ----------
static __device__ __forceinline__ f16x8 dequant8(uint32_t w, f16x2 sv, f16x2 zv) {
    uint32_t p0 = (w & 0x000F000Fu) | 0x64006400u;
    uint32_t p1 = ((w >> 4)  & 0x000F000Fu) | 0x64006400u;
    uint32_t p2 = ((w >> 8)  & 0x000F000Fu) | 0x64006400u;
    uint32_t p3 = ((w >> 12) & 0x000F000Fu) | 0x64006400u;
    f16x2 h0 = (__builtin_bit_cast(f16x2, p0) + zv) * sv;
    f16x2 h1 = (__builtin_bit_cast(f16x2, p1) + zv) * sv;
    f16x2 h2 = (__builtin_bit_cast(f16x2, p2) + zv) * sv;
    f16x2 h3 = (__builtin_bit_cast(f16x2, p3) + zv) * sv;
    f16x8 o;
    o[0] = h0[0]; o[1] = h0[1]; o[2] = h1[0]; o[3] = h1[1];
    o[4] = h2[0]; o[5] = h2[1]; o[6] = h3[0]; o[7] = h3[1];
    return o;
}

__global__ __launch_bounds__(512, 4) void qgemm_f16_fb(
    const float* __restrict__ x, const uint32_t* __restrict__ qweight,
    const uint32_t* __restrict__ qzeros, const int* __restrict__ qscales,
    const float* __restrict__ qscales_zeros, const float* __restrict__ qscales_scales,
    float* __restrict__ out)
{
    __shared__ __align__(16) f16 heap[2][(BM + BN) * 64];
    f16* const Ab0 = &heap[0][0];
    f16* const Ab1 = &heap[1][0];
    f16* const Bb0 = &heap[0][BM * 64];
    f16* const Bb1 = &heap[1][BM * 64];
    const int tid = threadIdx.x, lane = tid & 63, wid = tid >> 6;
    const int kg = wid >> 2, wm = (wid >> 1) & 1, wn = wid & 1;
    const int mt = blockIdx.x & 15, nt = blockIdx.x >> 4;
    const int m0 = mt * BM, n0 = nt * BN;
    const int colb = tid & 127, og2 = (tid >> 7) << 1, ncol = n0 + colb;
    const float ssv = qscales_scales[ncol], qzssv = qscales_zeros[ncol] * ssv;
    int bo[2];
    #pragma unroll
    for (int r = 0; r < 2; ++r) bo[r] = colb * 64 + ((og2 + r) ^ (colb & 7)) * 8;
    const uint32_t* bptr = qweight + (size_t)og2 * OUT_F + ncol;
    const int arow = tid >> 3, aoct = (tid & 7) ^ (arow & 7);
    const float* fsrc0 = x + (size_t)(m0 + arow) * IN_F + aoct * 8;
    const int aoff0 = tid * 8, aoff1 = (tid + 512) * 8;
    const int lr = lane & 15, lo = lane >> 4, koct = kg * 4 + lo;
    int offA[4], offB[4];
    #pragma unroll
    for (int f = 0; f < 4; ++f) {
        const int ra = wm * 64 + f * 16 + lr;
        offA[f] = ra * 64 + (koct ^ (ra & 7)) * 8;
        const int rb = wn * 64 + f * 16 + lr;
        offB[f] = rb * 64 + (koct ^ (rb & 7)) * 8;
    }
    f32x4 acc[4][4];
    #pragma unroll
    for (int i = 0; i < 4; ++i)
        #pragma unroll
        for (int j = 0; j < 4; ++j) { f32x4 z = {0,0,0,0}; acc[i][j] = z; }
    auto load_bw = [&](int t_, uint32_t* w) {
        const uint32_t* p = bptr + (size_t)t_ * 8 * OUT_F;
        w[0] = p[0]; w[1] = p[OUT_F];
    };
    auto mkc = [&](f16x2& sv_, f16x2& zv_, int sw_, uint32_t zw_) {
        const float sf = (float)sw_ * ssv - qzssv;
        const int z = (int)((zw_ >> ((ncol & 7) * 4)) & 0xFu);
        const f16 sh = (f16)sf, zh = (f16)(float)(-(1025 + z));
        sv_[0] = sh; sv_[1] = sh; zv_[0] = zh; zv_[1] = zh;
    };
    auto stage_B = [&](f16* Bb, const uint32_t* w, f16x2 sv_, f16x2 zv_) {
        *reinterpret_cast<f16x8*>(&Bb[bo[0]]) = dequant8(w[0], sv_, zv_);
        *reinterpret_cast<f16x8*>(&Bb[bo[1]]) = dequant8(w[1], sv_, zv_);
    };
    auto stage_A = [&](f16* Ab, int t_) {
        #pragma unroll
        for (int i = 0; i < 2; ++i) {
            const float* p = fsrc0 + (size_t)t_ * 64 + (size_t)(64 * i) * IN_F;
            const float4 v0 = *reinterpret_cast<const float4*>(p);
            const float4 v1 = *reinterpret_cast<const float4*>(p + 4);
            f16x8 v;
            v[0] = (f16)v0.x; v[1] = (f16)v1.x; v[2] = (f16)v0.y; v[3] = (f16)v1.y;
            v[4] = (f16)v0.z; v[5] = (f16)v1.z; v[6] = (f16)v0.w; v[7] = (f16)v1.w;
            *reinterpret_cast<f16x8*>(&Ab[i == 0 ? aoff0 : aoff1]) = v;
        }
    };
    auto compute = [&](const f16* Ab, const f16* Bb) {
        f16x8 af[4], bf[4];
        #pragma unroll
        for (int f = 0; f < 4; ++f) af[f] = *reinterpret_cast<const f16x8*>(&Ab[offA[f]]);
        #pragma unroll
        for (int f = 0; f < 4; ++f) bf[f] = *reinterpret_cast<const f16x8*>(&Bb[offB[f]]);
        #pragma unroll
        for (int i = 0; i < 4; ++i)
            #pragma unroll
            for (int j = 0; j < 4; ++j)
                acc[i][j] = __builtin_amdgcn_mfma_f32_16x16x32_f16(af[i], bf[j], acc[i][j], 0, 0, 0);
    };
    uint32_t wcur[2], wnxt[2];
    int swN; uint32_t zwN;
    f16x2 sv, zv, svN, zvN;
    {
        uint32_t w0[2];
        load_bw(0, w0);
        const int sw0 = qscales[ncol];
        const uint32_t zw0 = qzeros[ncol >> 3];
        stage_A(Ab0, 0);
        load_bw(1, wcur);
        swN = qscales[OUT_F + ncol]; zwN = qzeros[OPW + (ncol >> 3)];
        mkc(sv, zv, sw0, zw0);
        stage_B(Bb0, w0, sv, zv);
        asm volatile("s_waitcnt lgkmcnt(0)" ::: "memory");
        __builtin_amdgcn_s_barrier();
    }
    for (int t = 0; t < 64; t += 2) {
        mkc(svN, zvN, swN, zwN);
        stage_B(Bb1, wcur, sv, zv);
        stage_A(Ab1, t + 1);
        load_bw(t + 2 < 64 ? t + 2 : 63, wnxt);
        {
            const int g2 = (t >> 1) + 2 < NGROUP ? (t >> 1) + 2 : NGROUP - 1;
            swN = qscales[(size_t)g2 * OUT_F + ncol];
            zwN = qzeros[(size_t)g2 * OPW + (ncol >> 3)];
        }
        compute(Ab0, Bb0);
        asm volatile("s_waitcnt lgkmcnt(0)" ::: "memory");
        __builtin_amdgcn_s_barrier();
        sv = svN; zv = zvN;
        stage_B(Bb0, wnxt, sv, zv);
        stage_A(Ab0, t + 2 < 64 ? t + 2 : 63);
        load_bw(t + 3 < 64 ? t + 3 : 63, wcur);
        compute(Ab1, Bb1);
        asm volatile("s_waitcnt lgkmcnt(0)" ::: "memory");
        __builtin_amdgcn_s_barrier();
    }
    __syncthreads();
    f32x4* scratch = reinterpret_cast<f32x4*>(&heap[0][0]);
    const int wpos = wid & 3;
    #pragma unroll
    for (int h = 0; h < 2; ++h) {
        if (kg == 1) {
            #pragma unroll
            for (int di = 0; di < 2; ++di)
                #pragma unroll
                for (int j = 0; j < 4; ++j)
                    scratch[wpos * 512 + (di * 4 + j) * 64 + lane] = acc[2 * h + di][j];
        }
        __syncthreads();
        if (kg == 0) {
            #pragma unroll
            for (int di = 0; di < 2; ++di)
                #pragma unroll
                for (int j = 0; j < 4; ++j) {
                    const f32x4 p = scratch[wpos * 512 + (di * 4 + j) * 64 + lane];
                    acc[2 * h + di][j].x += p.x; acc[2 * h + di][j].y += p.y;
                    acc[2 * h + di][j].z += p.z; acc[2 * h + di][j].w += p.w;
                }
        }
        __syncthreads();
    }
    if (kg == 0) {
        const int orow = m0 + wm * 64 + lo * 4;
        const int ocol = n0 + wn * 64 + lr;
        #pragma unroll
        for (int i = 0; i < 4; ++i)
            #pragma unroll
            for (int j = 0; j < 4; ++j)
                #pragma unroll
                for (int r = 0; r < 4; ++r)
                    out[(size_t)(orow + i * 16 + r) * OUT_F + ocol + j * 16] = acc[i][j][r];
    }
}

extern "C" void kernel_launch(void* const* d_in, const int* in_sizes, int n_in,
                              void* d_out, int out_size, void* d_ws, size_t ws_size,
                              hipStream_t stream) {
    const float*    xp  = (const float*)d_in[0];
    const uint32_t* qw  = (const uint32_t*)d_in[1];
    const uint32_t* qz  = (const uint32_t*)d_in[2];
    const int*      qs  = (const int*)d_in[3];
    const float*    qsz = (const float*)d_in[4];
    const float*    qss = (const float*)d_in[5];
    // d_in[6] = g_idx: identity grouping (k/128), folded into the kernel.
    float* outp = (float*)d_out;

    const int grid = (TOKENS / BM) * (OUT_F / BN);   // 1376
    const size_t need = (size_t)TOKENS * IN_F + (size_t)TOKENS * 4;   // xi + a

    if (ws_size >= need) {
        char*  xi  = (char*)d_ws;
        float* aws = (float*)(xi + (size_t)TOKENS * IN_F);
        quant_x_kernel<<<TOKENS, 256, 0, stream>>>(xp, xi, aws);
        qgemm_i8_kernel<<<grid, 512, 0, stream>>>(xi, aws, qw, qz, qs, qsz, qss, outp);
    } else {
        qgemm_f16_fb<<<grid, 512, 0, stream>>>(xp, qw, qz, qs, qsz, qss, outp);
    }
}

// Round 16
// 870.349 us; speedup vs baseline: 1.8392x; 1.8392x over previous
//
#include <hip/hip_runtime.h>
#include <hip/hip_fp16.h>
#include <stdint.h>

#define IN_F   4096
#define OUT_F  11008
#define TOKENS 2048
#define BM 128
#define BN 128
#define BK2 128            // i8 K-tile == group size
#define NT2 (IN_F / BK2)   // 32 tiles (= groups)
#define NGROUP 32
#define OPW (OUT_F / 8)

typedef _Float16 f16;
typedef __attribute__((ext_vector_type(2))) _Float16 f16x2;
typedef __attribute__((ext_vector_type(8))) _Float16 f16x8;
typedef __attribute__((ext_vector_type(4))) float f32x4;
typedef __attribute__((ext_vector_type(4))) int   i32x4;

typedef __attribute__((address_space(3))) uint32_t lds_u32_t;
typedef const __attribute__((address_space(1))) uint32_t glb_u32_t;

#define SB0() __builtin_amdgcn_sched_barrier(0)

static __device__ __forceinline__ void gload_lds16(const void* g, void* l) {
    __builtin_amdgcn_global_load_lds((glb_u32_t*)g, (lds_u32_t*)l, 16, 0, 0);
}

// ---------------- pre-pass: per-row i8 quantization of x (r15-verified) --------
// xi byte order per 16-elem unit: {0,2,4,6, 1,3,5,7, 8,10,12,14, 9,11,13,15}
__global__ __launch_bounds__(256) void quant_x_kernel(const float* __restrict__ x,
                                                      char* __restrict__ xi,
                                                      float* __restrict__ aws) {
    __shared__ float red[4];
    const int row = blockIdx.x;
    const int tid = threadIdx.x;
    const float* xr = x + (size_t)row * IN_F + tid * 16;
    float v[16];
    #pragma unroll
    for (int p = 0; p < 4; ++p) {
        const float4 t = *reinterpret_cast<const float4*>(xr + p * 4);
        v[p * 4 + 0] = t.x; v[p * 4 + 1] = t.y; v[p * 4 + 2] = t.z; v[p * 4 + 3] = t.w;
    }
    float m = 0.f;
    #pragma unroll
    for (int p = 0; p < 16; ++p) m = fmaxf(m, fabsf(v[p]));
    #pragma unroll
    for (int off = 32; off > 0; off >>= 1) m = fmaxf(m, __shfl_xor(m, off));
    if ((tid & 63) == 0) red[tid >> 6] = m;
    __syncthreads();
    m = fmaxf(fmaxf(red[0], red[1]), fmaxf(red[2], red[3]));
    const float a   = m * (1.0f / 127.0f);
    const float inv = (m > 0.f) ? 127.0f / m : 0.f;
    if (tid == 0) aws[row] = a;
    const float MAGIC = 12582912.0f;   // 1.5*2^23: RNE int in low byte
    uint32_t b[16];
    #pragma unroll
    for (int p = 0; p < 16; ++p)
        b[p] = __builtin_bit_cast(uint32_t, fmaf(v[p], inv, MAGIC)) & 0xFFu;
    i32x4 d;
    d[0] = (int)(b[0] | (b[2] << 8) | (b[4]  << 16) | (b[6]  << 24));
    d[1] = (int)(b[1] | (b[3] << 8) | (b[5]  << 16) | (b[7]  << 24));
    d[2] = (int)(b[8] | (b[10] << 8) | (b[12] << 16) | (b[14] << 24));
    d[3] = (int)(b[9] | (b[11] << 8) | (b[13] << 16) | (b[15] << 24));
    *reinterpret_cast<i32x4*>(xi + (size_t)row * IN_F + tid * 16) = d;
}

// ---------------- i8 GEMM v2: 64x32 wave-tiles, no k-split, flush/tile ---------
__global__ __launch_bounds__(512, 4) void qgemm_i8_kernel(
    const char*     __restrict__ xi,
    const float*    __restrict__ aws,
    const uint32_t* __restrict__ qweight,
    const uint32_t* __restrict__ qzeros,
    const int*      __restrict__ qscales,
    const float*    __restrict__ qscales_zeros,
    const float*    __restrict__ qscales_scales,
    float*          __restrict__ out)
{
    // A,B i8 [128][128]; 16B unit (row, slot) holds k-unit slot^(row&7) -> conflict-free
    __shared__ __align__(16) char Ash[2][BM * BK2];   // 2 x 16 KiB
    __shared__ __align__(16) char Bsh[2][BN * BK2];   // 2 x 16 KiB (64 KiB -> 2 blk/CU)

    const int tid  = threadIdx.x;
    const int lane = tid & 63;
    const int wid  = tid >> 6;        // 0..7
    const int wm   = wid >> 2;        // 0..1  (M half: 64 rows)
    const int wn   = wid & 3;         // 0..3  (N quarter: 32 cols)

    const int mt = blockIdx.x & 15;
    const int nt = blockIdx.x >> 4;
    const int m0 = mt * BM;
    const int n0 = nt * BN;

    // ---- B staging: thread owns col colb, units {h, h+4} (4 packed words/tile)
    const int colb = tid & 127;
    const int h    = tid >> 7;        // 0..3
    const int ncol = n0 + colb;
    const int boff0 = colb * BK2 + ((h)     ^ (colb & 7)) * 16;
    const int boff1 = colb * BK2 + ((h + 4) ^ (colb & 7)) * 16;
    const uint32_t* bptr = qweight + (size_t)(2 * h) * OUT_F + ncol;

    // ---- A staging: 2 chunks/thread, linear dest, swizzled source
    const int arow0 = tid >> 3, aslot0 = tid & 7;
    const int arow1 = (tid + 512) >> 3, aslot1 = (tid + 512) & 7;
    const char* asrc0 = xi + (size_t)(m0 + arow0) * IN_F + (aslot0 ^ (arow0 & 7)) * 16;
    const char* asrc1 = xi + (size_t)(m0 + arow1) * IN_F + (aslot1 ^ (arow1 & 7)) * 16;
    const int adst0 = tid * 16, adst1 = (tid + 512) * 16;

    // ---- fragment offsets: 2 k-steps (ks=0: units lo, ks=1: units lo+4)
    const int lr = lane & 15;
    const int lo = lane >> 4;         // 0..3
    int aoffr[2][4], boffr[2][2], cread[2];
    #pragma unroll
    for (int ks = 0; ks < 2; ++ks) {
        #pragma unroll
        for (int f = 0; f < 4; ++f) {
            const int ra = wm * 64 + f * 16 + lr;
            aoffr[ks][f] = ra * BK2 + ((ks * 4 + lo) ^ (ra & 7)) * 16;
        }
        #pragma unroll
        for (int j = 0; j < 2; ++j) {
            const int rb = wn * 32 + j * 16 + lr;
            boffr[ks][j] = rb * BK2 + ((ks * 4 + lo) ^ (rb & 7)) * 16;
        }
    }
    cread[0] = n0 + wn * 32 + lr;
    cread[1] = cread[0] + 16;
    float qszr[2], qssr[2];
    #pragma unroll
    for (int j = 0; j < 2; ++j) {
        qszr[j] = qscales_zeros[cread[j]];
        qssr[j] = qscales_scales[cread[j]];
    }

    f32x4 acc[4][2];
    #pragma unroll
    for (int i = 0; i < 4; ++i)
        #pragma unroll
        for (int j = 0; j < 2; ++j) {
            f32x4 z = {0.f, 0.f, 0.f, 0.f};
            acc[i][j] = z;
        }

    auto load_bw = [&](int t_, uint32_t* w) {
        const uint32_t* p = bptr + (size_t)t_ * 16 * OUT_F;
        w[0] = p[0];
        w[1] = p[OUT_F];
        w[2] = p[(size_t)8 * OUT_F];
        w[3] = p[(size_t)9 * OUT_F];
    };
    auto mk_kz = [&](uint32_t zw_) -> uint32_t {
        const uint32_t znib = (zw_ >> ((ncol & 7) * 4)) & 0xFu;
        return (127u - znib) * 0x01010101u;   // per-byte: +(128-(z+1)), then ^0x80
    };
    auto unpack16 = [&](uint32_t wa, uint32_t wb, uint32_t kz) -> i32x4 {
        i32x4 d;
        d[0] = (int)(((( wa      ) & 0x0F0F0F0Fu) + kz) ^ 0x80808080u);
        d[1] = (int)((((wa >> 4)  & 0x0F0F0F0Fu) + kz) ^ 0x80808080u);
        d[2] = (int)(((( wb      ) & 0x0F0F0F0Fu) + kz) ^ 0x80808080u);
        d[3] = (int)((((wb >> 4)  & 0x0F0F0F0Fu) + kz) ^ 0x80808080u);
        return d;
    };
    auto stage_B = [&](int buf, const uint32_t* w, uint32_t kz) {
        *reinterpret_cast<i32x4*>(&Bsh[buf][boff0]) = unpack16(w[0], w[1], kz);
        *reinterpret_cast<i32x4*>(&Bsh[buf][boff1]) = unpack16(w[2], w[3], kz);
    };
    auto stage_A = [&](int buf, int t_) {
        gload_lds16(asrc0 + (size_t)t_ * BK2, &Ash[buf][adst0]);
        gload_lds16(asrc1 + (size_t)t_ * BK2, &Ash[buf][adst1]);
    };
    // 16 MFMAs: D = mfma(ks0) then D = mfma(ks1, D); one f32 flush per tile.
    auto compute = [&](int buf, const float* sc) {
        i32x4 D[4][2];
        {
            i32x4 af[4], bf[2];
            #pragma unroll
            for (int f = 0; f < 4; ++f)
                af[f] = *reinterpret_cast<const i32x4*>(&Ash[buf][aoffr[0][f]]);
            #pragma unroll
            for (int j = 0; j < 2; ++j)
                bf[j] = *reinterpret_cast<const i32x4*>(&Bsh[buf][boffr[0][j]]);
            __builtin_amdgcn_s_setprio(1);
            #pragma unroll
            for (int i = 0; i < 4; ++i)
                #pragma unroll
                for (int j = 0; j < 2; ++j) {
                    i32x4 z0 = {0, 0, 0, 0};
                    D[i][j] = __builtin_amdgcn_mfma_i32_16x16x64_i8(af[i], bf[j], z0, 0, 0, 0);
                }
            __builtin_amdgcn_s_setprio(0);
        }
        {
            i32x4 af[4], bf[2];
            #pragma unroll
            for (int f = 0; f < 4; ++f)
                af[f] = *reinterpret_cast<const i32x4*>(&Ash[buf][aoffr[1][f]]);
            #pragma unroll
            for (int j = 0; j < 2; ++j)
                bf[j] = *reinterpret_cast<const i32x4*>(&Bsh[buf][boffr[1][j]]);
            __builtin_amdgcn_s_setprio(1);
            #pragma unroll
            for (int i = 0; i < 4; ++i)
                #pragma unroll
                for (int j = 0; j < 2; ++j)
                    D[i][j] = __builtin_amdgcn_mfma_i32_16x16x64_i8(af[i], bf[j], D[i][j], 0, 0, 0);
            __builtin_amdgcn_s_setprio(0);
        }
        #pragma unroll
        for (int i = 0; i < 4; ++i)
            #pragma unroll
            for (int j = 0; j < 2; ++j) {
                acc[i][j].x += sc[j] * (float)D[i][j][0];
                acc[i][j].y += sc[j] * (float)D[i][j][1];
                acc[i][j].z += sc[j] * (float)D[i][j][2];
                acc[i][j].w += sc[j] * (float)D[i][j][3];
            }
    };

    uint32_t wE[4], wO[4];
    uint32_t zwE, zwO;
    int sfE[2], sfO[2];

    // -------- prologue --------
    {
        uint32_t w0[4];
        load_bw(0, w0);
        const uint32_t kz0 = mk_kz(qzeros[ncol >> 3]);   // group 0 (staged tile 0)
        stage_A(0, 0);
        stage_B(0, w0, kz0);
        load_bw(1, wE);                                  // words tile 1
        zwE = qzeros[OPW + (ncol >> 3)];                 // zeros group 1
        #pragma unroll
        for (int j = 0; j < 2; ++j) sfE[j] = qscales[cread[j]];   // flush scales g0
        asm volatile("s_waitcnt vmcnt(0)" ::: "memory");
        asm volatile("s_waitcnt lgkmcnt(0)" ::: "memory");
        __builtin_amdgcn_s_barrier();
    }

// body T (buf C): flush scales SFC (group T); stage tile T+1 with WC + zeros ZC
// (group T+1); prefetch words(T+2)->WL, zeros(T+2)->ZL, scales(T+1)->SFL.
// vmcnt(7): retires the 2 A-gloads, leaves [4 bw + 1 zw + 2 sc] in flight.
#define BODY(C, T, WC, ZC, SFC, WL, ZL, SFL)                                      \
  {                                                                               \
    const int tn1_ = ((T) + 1 < NT2) ? (T) + 1 : NT2 - 1;                         \
    const int tn2_ = ((T) + 2 < NT2) ? (T) + 2 : NT2 - 1;                         \
    float scur_[2];                                                               \
    _Pragma("unroll") for (int j = 0; j < 2; ++j)                                 \
      scur_[j] = ((float)SFC[j] - qszr[j]) * qssr[j];                             \
    const uint32_t kz_ = mk_kz(ZC);                                               \
    stage_B((C) ^ 1, WC, kz_);                                                    \
    SB0();                                                                        \
    stage_A((C) ^ 1, tn1_);                                                       \
    SB0();                                                                        \
    load_bw(tn2_, WL);                                                            \
    ZL = qzeros[(size_t)tn2_ * OPW + (ncol >> 3)];                                \
    _Pragma("unroll") for (int j = 0; j < 2; ++j)                                 \
      SFL[j] = qscales[(size_t)tn1_ * OUT_F + cread[j]];                          \
    SB0();                                                                        \
    compute(C, scur_);                                                            \
    asm volatile("s_waitcnt vmcnt(7)" ::: "memory");                              \
    asm volatile("s_waitcnt lgkmcnt(0)" ::: "memory");                            \
    __builtin_amdgcn_s_barrier();                                                 \
  }

    for (int t = 0; t < NT2; t += 2) {
        BODY(0, t,     wE, zwE, sfE, wO, zwO, sfO)
        BODY(1, t + 1, wO, zwO, sfO, wE, zwE, sfE)
    }
#undef BODY

    // -------- epilogue: C/D col=lane&15, row=(lane>>4)*4+reg; apply a[m] --------
    const int orow = m0 + wm * 64 + lo * 4;
    const int ocol = n0 + wn * 32 + lr;
    #pragma unroll
    for (int i = 0; i < 4; ++i)
        #pragma unroll
        for (int j = 0; j < 2; ++j)
            #pragma unroll
            for (int r = 0; r < 4; ++r) {
                const int rr = orow + i * 16 + r;
                out[(size_t)rr * OUT_F + ocol + j * 16] = aws[rr] * acc[i][j][r];
            }
}

// ---------------- fallback (no workspace): r10-style f16 kernel ----------------
static __device__ __forceinline__ f16x8 dequant8(uint32_t w, f16x2 sv, f16x2 zv) {
    uint32_t p0 = (w & 0x000F000Fu) | 0x64006400u;
    uint32_t p1 = ((w >> 4)  & 0x000F000Fu) | 0x64006400u;
    uint32_t p2 = ((w >> 8)  & 0x000F000Fu) | 0x64006400u;
    uint32_t p3 = ((w >> 12) & 0x000F000Fu) | 0x64006400u;
    f16x2 h0 = (__builtin_bit_cast(f16x2, p0) + zv) * sv;
    f16x2 h1 = (__builtin_bit_cast(f16x2, p1) + zv) * sv;
    f16x2 h2 = (__builtin_bit_cast(f16x2, p2) + zv) * sv;
    f16x2 h3 = (__builtin_bit_cast(f16x2, p3) + zv) * sv;
    f16x8 o;
    o[0] = h0[0]; o[1] = h0[1]; o[2] = h1[0]; o[3] = h1[1];
    o[4] = h2[0]; o[5] = h2[1]; o[6] = h3[0]; o[7] = h3[1];
    return o;
}

__global__ __launch_bounds__(512, 4) void qgemm_f16_fb(
    const float* __restrict__ x, const uint32_t* __restrict__ qweight,
    const uint32_t* __restrict__ qzeros, const int* __restrict__ qscales,
    const float* __restrict__ qscales_zeros, const float* __restrict__ qscales_scales,
    float* __restrict__ out)
{
    __shared__ __align__(16) f16 heap[2][(BM + BN) * 64];
    f16* const Ab0 = &heap[0][0];
    f16* const Ab1 = &heap[1][0];
    f16* const Bb0 = &heap[0][BM * 64];
    f16* const Bb1 = &heap[1][BM * 64];
    const int tid = threadIdx.x, lane = tid & 63, wid = tid >> 6;
    const int kg = wid >> 2, wm = (wid >> 1) & 1, wn = wid & 1;
    const int mt = blockIdx.x & 15, nt = blockIdx.x >> 4;
    const int m0 = mt * BM, n0 = nt * BN;
    const int colb = tid & 127, og2 = (tid >> 7) << 1, ncol = n0 + colb;
    const float ssv = qscales_scales[ncol], qzssv = qscales_zeros[ncol] * ssv;
    int bo[2];
    #pragma unroll
    for (int r = 0; r < 2; ++r) bo[r] = colb * 64 + ((og2 + r) ^ (colb & 7)) * 8;
    const uint32_t* bptr = qweight + (size_t)og2 * OUT_F + ncol;
    const int arow = tid >> 3, aoct = (tid & 7) ^ (arow & 7);
    const float* fsrc0 = x + (size_t)(m0 + arow) * IN_F + aoct * 8;
    const int aoff0 = tid * 8, aoff1 = (tid + 512) * 8;
    const int lr = lane & 15, lo = lane >> 4, koct = kg * 4 + lo;
    int offA[4], offB[4];
    #pragma unroll
    for (int f = 0; f < 4; ++f) {
        const int ra = wm * 64 + f * 16 + lr;
        offA[f] = ra * 64 + (koct ^ (ra & 7)) * 8;
        const int rb = wn * 64 + f * 16 + lr;
        offB[f] = rb * 64 + (koct ^ (rb & 7)) * 8;
    }
    f32x4 acc[4][4];
    #pragma unroll
    for (int i = 0; i < 4; ++i)
        #pragma unroll
        for (int j = 0; j < 4; ++j) { f32x4 z = {0,0,0,0}; acc[i][j] = z; }
    auto load_bw = [&](int t_, uint32_t* w) {
        const uint32_t* p = bptr + (size_t)t_ * 8 * OUT_F;
        w[0] = p[0]; w[1] = p[OUT_F];
    };
    auto mkc = [&](f16x2& sv_, f16x2& zv_, int sw_, uint32_t zw_) {
        const float sf = (float)sw_ * ssv - qzssv;
        const int z = (int)((zw_ >> ((ncol & 7) * 4)) & 0xFu);
        const f16 sh = (f16)sf, zh = (f16)(float)(-(1025 + z));
        sv_[0] = sh; sv_[1] = sh; zv_[0] = zh; zv_[1] = zh;
    };
    auto stage_B = [&](f16* Bb, const uint32_t* w, f16x2 sv_, f16x2 zv_) {
        *reinterpret_cast<f16x8*>(&Bb[bo[0]]) = dequant8(w[0], sv_, zv_);
        *reinterpret_cast<f16x8*>(&Bb[bo[1]]) = dequant8(w[1], sv_, zv_);
    };
    auto stage_A = [&](f16* Ab, int t_) {
        #pragma unroll
        for (int i = 0; i < 2; ++i) {
            const float* p = fsrc0 + (size_t)t_ * 64 + (size_t)(64 * i) * IN_F;
            const float4 v0 = *reinterpret_cast<const float4*>(p);
            const float4 v1 = *reinterpret_cast<const float4*>(p + 4);
            f16x8 v;
            v[0] = (f16)v0.x; v[1] = (f16)v1.x; v[2] = (f16)v0.y; v[3] = (f16)v1.y;
            v[4] = (f16)v0.z; v[5] = (f16)v1.z; v[6] = (f16)v0.w; v[7] = (f16)v1.w;
            *reinterpret_cast<f16x8*>(&Ab[i == 0 ? aoff0 : aoff1]) = v;
        }
    };
    auto compute = [&](const f16* Ab, const f16* Bb) {
        f16x8 af[4], bf[4];
        #pragma unroll
        for (int f = 0; f < 4; ++f) af[f] = *reinterpret_cast<const f16x8*>(&Ab[offA[f]]);
        #pragma unroll
        for (int f = 0; f < 4; ++f) bf[f] = *reinterpret_cast<const f16x8*>(&Bb[offB[f]]);
        #pragma unroll
        for (int i = 0; i < 4; ++i)
            #pragma unroll
            for (int j = 0; j < 4; ++j)
                acc[i][j] = __builtin_amdgcn_mfma_f32_16x16x32_f16(af[i], bf[j], acc[i][j], 0, 0, 0);
    };
    uint32_t wcur[2], wnxt[2];
    int swN; uint32_t zwN;
    f16x2 sv, zv, svN, zvN;
    {
        uint32_t w0[2];
        load_bw(0, w0);
        const int sw0 = qscales[ncol];
        const uint32_t zw0 = qzeros[ncol >> 3];
        stage_A(Ab0, 0);
        load_bw(1, wcur);
        swN = qscales[OUT_F + ncol]; zwN = qzeros[OPW + (ncol >> 3)];
        mkc(sv, zv, sw0, zw0);
        stage_B(Bb0, w0, sv, zv);
        asm volatile("s_waitcnt lgkmcnt(0)" ::: "memory");
        __builtin_amdgcn_s_barrier();
    }
    for (int t = 0; t < 64; t += 2) {
        mkc(svN, zvN, swN, zwN);
        stage_B(Bb1, wcur, sv, zv);
        stage_A(Ab1, t + 1);
        load_bw(t + 2 < 64 ? t + 2 : 63, wnxt);
        {
            const int g2 = (t >> 1) + 2 < NGROUP ? (t >> 1) + 2 : NGROUP - 1;
            swN = qscales[(size_t)g2 * OUT_F + ncol];
            zwN = qzeros[(size_t)g2 * OPW + (ncol >> 3)];
        }
        compute(Ab0, Bb0);
        asm volatile("s_waitcnt lgkmcnt(0)" ::: "memory");
        __builtin_amdgcn_s_barrier();
        sv = svN; zv = zvN;
        stage_B(Bb0, wnxt, sv, zv);
        stage_A(Ab0, t + 2 < 64 ? t + 2 : 63);
        load_bw(t + 3 < 64 ? t + 3 : 63, wcur);
        compute(Ab1, Bb1);
        asm volatile("s_waitcnt lgkmcnt(0)" ::: "memory");
        __builtin_amdgcn_s_barrier();
    }
    __syncthreads();
    f32x4* scratch = reinterpret_cast<f32x4*>(&heap[0][0]);
    const int wpos = wid & 3;
    #pragma unroll
    for (int hh = 0; hh < 2; ++hh) {
        if (kg == 1) {
            #pragma unroll
            for (int di = 0; di < 2; ++di)
                #pragma unroll
                for (int j = 0; j < 4; ++j)
                    scratch[wpos * 512 + (di * 4 + j) * 64 + lane] = acc[2 * hh + di][j];
        }
        __syncthreads();
        if (kg == 0) {
            #pragma unroll
            for (int di = 0; di < 2; ++di)
                #pragma unroll
                for (int j = 0; j < 4; ++j) {
                    const f32x4 p = scratch[wpos * 512 + (di * 4 + j) * 64 + lane];
                    acc[2 * hh + di][j].x += p.x; acc[2 * hh + di][j].y += p.y;
                    acc[2 * hh + di][j].z += p.z; acc[2 * hh + di][j].w += p.w;
                }
        }
        __syncthreads();
    }
    if (kg == 0) {
        const int orow = m0 + wm * 64 + lo * 4;
        const int ocol = n0 + wn * 64 + lr;
        #pragma unroll
        for (int i = 0; i < 4; ++i)
            #pragma unroll
            for (int j = 0; j < 4; ++j)
                #pragma unroll
                for (int r = 0; r < 4; ++r)
                    out[(size_t)(orow + i * 16 + r) * OUT_F + ocol + j * 16] = acc[i][j][r];
    }
}

extern "C" void kernel_launch(void* const* d_in, const int* in_sizes, int n_in,
                              void* d_out, int out_size, void* d_ws, size_t ws_size,
                              hipStream_t stream) {
    const float*    xp  = (const float*)d_in[0];
    const uint32_t* qw  = (const uint32_t*)d_in[1];
    const uint32_t* qz  = (const uint32_t*)d_in[2];
    const int*      qs  = (const int*)d_in[3];
    const float*    qsz = (const float*)d_in[4];
    const float*    qss = (const float*)d_in[5];
    // d_in[6] = g_idx: identity grouping (k/128), folded into the kernel.
    float* outp = (float*)d_out;

    const int grid = (TOKENS / BM) * (OUT_F / BN);   // 1376
    const size_t need = (size_t)TOKENS * IN_F + (size_t)TOKENS * 4;   // xi + a

    if (ws_size >= need) {
        char*  xi  = (char*)d_ws;
        float* aws = (float*)(xi + (size_t)TOKENS * IN_F);
        quant_x_kernel<<<TOKENS, 256, 0, stream>>>(xp, xi, aws);
        qgemm_i8_kernel<<<grid, 512, 0, stream>>>(xi, aws, qw, qz, qs, qsz, qss, outp);
    } else {
        qgemm_f16_fb<<<grid, 512, 0, stream>>>(xp, qw, qz, qs, qsz, qss, outp);
    }
}

// Round 17
// 211.440 us; speedup vs baseline: 7.5706x; 4.1163x over previous
//
#include <hip/hip_runtime.h>
#include <hip/hip_fp16.h>
#include <stdint.h>

#define IN_F   4096
#define OUT_F  11008
#define TOKENS 2048
#define BM 128
#define BN 128
#define BK2 128            // i8 K-tile == group size
#define NT2 (IN_F / BK2)   // 32 tiles (= groups)
#define NGROUP 32
#define OPW (OUT_F / 8)

typedef _Float16 f16;
typedef __attribute__((ext_vector_type(2))) _Float16 f16x2;
typedef __attribute__((ext_vector_type(8))) _Float16 f16x8;
typedef __attribute__((ext_vector_type(4))) float f32x4;
typedef __attribute__((ext_vector_type(4))) int   i32x4;

typedef __attribute__((address_space(3))) uint32_t lds_u32_t;
typedef const __attribute__((address_space(1))) uint32_t glb_u32_t;

#define SB0() __builtin_amdgcn_sched_barrier(0)

static __device__ __forceinline__ void gload_lds16(const void* g, void* l) {
    __builtin_amdgcn_global_load_lds((glb_u32_t*)g, (lds_u32_t*)l, 16, 0, 0);
}

// ---------------- pre-pass: per-row i8 quantization of x (r15-verified) --------
// xi byte order per 16-elem unit: {0,2,4,6, 1,3,5,7, 8,10,12,14, 9,11,13,15}
__global__ __launch_bounds__(256) void quant_x_kernel(const float* __restrict__ x,
                                                      char* __restrict__ xi,
                                                      float* __restrict__ aws) {
    __shared__ float red[4];
    const int row = blockIdx.x;
    const int tid = threadIdx.x;
    const float* xr = x + (size_t)row * IN_F + tid * 16;
    float v[16];
    #pragma unroll
    for (int p = 0; p < 4; ++p) {
        const float4 t = *reinterpret_cast<const float4*>(xr + p * 4);
        v[p * 4 + 0] = t.x; v[p * 4 + 1] = t.y; v[p * 4 + 2] = t.z; v[p * 4 + 3] = t.w;
    }
    float m = 0.f;
    #pragma unroll
    for (int p = 0; p < 16; ++p) m = fmaxf(m, fabsf(v[p]));
    #pragma unroll
    for (int off = 32; off > 0; off >>= 1) m = fmaxf(m, __shfl_xor(m, off));
    if ((tid & 63) == 0) red[tid >> 6] = m;
    __syncthreads();
    m = fmaxf(fmaxf(red[0], red[1]), fmaxf(red[2], red[3]));
    const float a   = m * (1.0f / 127.0f);
    const float inv = (m > 0.f) ? 127.0f / m : 0.f;
    if (tid == 0) aws[row] = a;
    const float MAGIC = 12582912.0f;   // 1.5*2^23: RNE int in low byte
    uint32_t b[16];
    #pragma unroll
    for (int p = 0; p < 16; ++p)
        b[p] = __builtin_bit_cast(uint32_t, fmaf(v[p], inv, MAGIC)) & 0xFFu;
    i32x4 d;
    d[0] = (int)(b[0] | (b[2] << 8) | (b[4]  << 16) | (b[6]  << 24));
    d[1] = (int)(b[1] | (b[3] << 8) | (b[5]  << 16) | (b[7]  << 24));
    d[2] = (int)(b[8] | (b[10] << 8) | (b[12] << 16) | (b[14] << 24));
    d[3] = (int)(b[9] | (b[11] << 8) | (b[13] << 16) | (b[15] << 24));
    *reinterpret_cast<i32x4*>(xi + (size_t)row * IN_F + tid * 16) = d;
}

// ---------------- i8 GEMM v2: 64x32 wave-tiles, no k-split, flush/tile ---------
// launch_bounds(512, 2): VGPR cap 128 (the (512,4) form capped at 64 -> spill).
__global__ __launch_bounds__(512, 2) void qgemm_i8_kernel(
    const char*     __restrict__ xi,
    const float*    __restrict__ aws,
    const uint32_t* __restrict__ qweight,
    const uint32_t* __restrict__ qzeros,
    const int*      __restrict__ qscales,
    const float*    __restrict__ qscales_zeros,
    const float*    __restrict__ qscales_scales,
    float*          __restrict__ out)
{
    // A,B i8 [128][128]; 16B unit (row, slot) holds k-unit slot^(row&7) -> conflict-free
    __shared__ __align__(16) char Ash[2][BM * BK2];   // 2 x 16 KiB
    __shared__ __align__(16) char Bsh[2][BN * BK2];   // 2 x 16 KiB (64 KiB -> 2 blk/CU)

    const int tid  = threadIdx.x;
    const int lane = tid & 63;
    const int wid  = tid >> 6;        // 0..7
    const int wm   = wid >> 2;        // 0..1  (M half: 64 rows)
    const int wn   = wid & 3;         // 0..3  (N quarter: 32 cols)

    const int mt = blockIdx.x & 15;
    const int nt = blockIdx.x >> 4;
    const int m0 = mt * BM;
    const int n0 = nt * BN;

    // ---- B staging: thread owns col colb, units {h, h+4} (4 packed words/tile)
    const int colb = tid & 127;
    const int h    = tid >> 7;        // 0..3
    const int ncol = n0 + colb;
    const int boff0 = colb * BK2 + ((h)     ^ (colb & 7)) * 16;
    const int boff1 = colb * BK2 + ((h + 4) ^ (colb & 7)) * 16;
    const uint32_t* bptr = qweight + (size_t)(2 * h) * OUT_F + ncol;

    // ---- A staging: 2 chunks/thread, linear dest, swizzled source
    const int arow0 = tid >> 3, aslot0 = tid & 7;
    const int arow1 = (tid + 512) >> 3, aslot1 = (tid + 512) & 7;
    const char* asrc0 = xi + (size_t)(m0 + arow0) * IN_F + (aslot0 ^ (arow0 & 7)) * 16;
    const char* asrc1 = xi + (size_t)(m0 + arow1) * IN_F + (aslot1 ^ (arow1 & 7)) * 16;
    const int adst0 = tid * 16, adst1 = (tid + 512) * 16;

    // ---- fragment offsets: 2 k-steps (ks=0: units lo, ks=1: units lo+4)
    const int lr = lane & 15;
    const int lo = lane >> 4;         // 0..3
    int aoffr[2][4], boffr[2][2], cread[2];
    #pragma unroll
    for (int ks = 0; ks < 2; ++ks) {
        #pragma unroll
        for (int f = 0; f < 4; ++f) {
            const int ra = wm * 64 + f * 16 + lr;
            aoffr[ks][f] = ra * BK2 + ((ks * 4 + lo) ^ (ra & 7)) * 16;
        }
        #pragma unroll
        for (int j = 0; j < 2; ++j) {
            const int rb = wn * 32 + j * 16 + lr;
            boffr[ks][j] = rb * BK2 + ((ks * 4 + lo) ^ (rb & 7)) * 16;
        }
    }
    cread[0] = n0 + wn * 32 + lr;
    cread[1] = cread[0] + 16;
    float qszr[2], qssr[2];
    #pragma unroll
    for (int j = 0; j < 2; ++j) {
        qszr[j] = qscales_zeros[cread[j]];
        qssr[j] = qscales_scales[cread[j]];
    }

    f32x4 acc[4][2];
    #pragma unroll
    for (int i = 0; i < 4; ++i)
        #pragma unroll
        for (int j = 0; j < 2; ++j) {
            f32x4 z = {0.f, 0.f, 0.f, 0.f};
            acc[i][j] = z;
        }

    auto load_bw = [&](int t_, uint32_t* w) {
        const uint32_t* p = bptr + (size_t)t_ * 16 * OUT_F;
        w[0] = p[0];
        w[1] = p[OUT_F];
        w[2] = p[(size_t)8 * OUT_F];
        w[3] = p[(size_t)9 * OUT_F];
    };
    auto mk_kz = [&](uint32_t zw_) -> uint32_t {
        const uint32_t znib = (zw_ >> ((ncol & 7) * 4)) & 0xFu;
        return (127u - znib) * 0x01010101u;   // per-byte: +(128-(z+1)), then ^0x80
    };
    auto unpack16 = [&](uint32_t wa, uint32_t wb, uint32_t kz) -> i32x4 {
        i32x4 d;
        d[0] = (int)(((( wa      ) & 0x0F0F0F0Fu) + kz) ^ 0x80808080u);
        d[1] = (int)((((wa >> 4)  & 0x0F0F0F0Fu) + kz) ^ 0x80808080u);
        d[2] = (int)(((( wb      ) & 0x0F0F0F0Fu) + kz) ^ 0x80808080u);
        d[3] = (int)((((wb >> 4)  & 0x0F0F0F0Fu) + kz) ^ 0x80808080u);
        return d;
    };
    auto stage_B = [&](int buf, const uint32_t* w, uint32_t kz) {
        *reinterpret_cast<i32x4*>(&Bsh[buf][boff0]) = unpack16(w[0], w[1], kz);
        *reinterpret_cast<i32x4*>(&Bsh[buf][boff1]) = unpack16(w[2], w[3], kz);
    };
    auto stage_A = [&](int buf, int t_) {
        gload_lds16(asrc0 + (size_t)t_ * BK2, &Ash[buf][adst0]);
        gload_lds16(asrc1 + (size_t)t_ * BK2, &Ash[buf][adst1]);
    };
    // 16 MFMAs: D = mfma(ks0) then D = mfma(ks1, D); one f32 flush per tile.
    auto compute = [&](int buf, const float* sc) {
        i32x4 D[4][2];
        {
            i32x4 af[4], bf[2];
            #pragma unroll
            for (int f = 0; f < 4; ++f)
                af[f] = *reinterpret_cast<const i32x4*>(&Ash[buf][aoffr[0][f]]);
            #pragma unroll
            for (int j = 0; j < 2; ++j)
                bf[j] = *reinterpret_cast<const i32x4*>(&Bsh[buf][boffr[0][j]]);
            __builtin_amdgcn_s_setprio(1);
            #pragma unroll
            for (int i = 0; i < 4; ++i)
                #pragma unroll
                for (int j = 0; j < 2; ++j) {
                    i32x4 z0 = {0, 0, 0, 0};
                    D[i][j] = __builtin_amdgcn_mfma_i32_16x16x64_i8(af[i], bf[j], z0, 0, 0, 0);
                }
            __builtin_amdgcn_s_setprio(0);
        }
        {
            i32x4 af[4], bf[2];
            #pragma unroll
            for (int f = 0; f < 4; ++f)
                af[f] = *reinterpret_cast<const i32x4*>(&Ash[buf][aoffr[1][f]]);
            #pragma unroll
            for (int j = 0; j < 2; ++j)
                bf[j] = *reinterpret_cast<const i32x4*>(&Bsh[buf][boffr[1][j]]);
            __builtin_amdgcn_s_setprio(1);
            #pragma unroll
            for (int i = 0; i < 4; ++i)
                #pragma unroll
                for (int j = 0; j < 2; ++j)
                    D[i][j] = __builtin_amdgcn_mfma_i32_16x16x64_i8(af[i], bf[j], D[i][j], 0, 0, 0);
            __builtin_amdgcn_s_setprio(0);
        }
        #pragma unroll
        for (int i = 0; i < 4; ++i)
            #pragma unroll
            for (int j = 0; j < 2; ++j) {
                acc[i][j].x += sc[j] * (float)D[i][j][0];
                acc[i][j].y += sc[j] * (float)D[i][j][1];
                acc[i][j].z += sc[j] * (float)D[i][j][2];
                acc[i][j].w += sc[j] * (float)D[i][j][3];
            }
    };

    uint32_t wE[4], wO[4];
    uint32_t zwE, zwO;
    int sfE[2], sfO[2];

    // -------- prologue --------
    {
        uint32_t w0[4];
        load_bw(0, w0);
        const uint32_t kz0 = mk_kz(qzeros[ncol >> 3]);   // group 0 (staged tile 0)
        stage_A(0, 0);
        stage_B(0, w0, kz0);
        load_bw(1, wE);                                  // words tile 1
        zwE = qzeros[OPW + (ncol >> 3)];                 // zeros group 1
        #pragma unroll
        for (int j = 0; j < 2; ++j) sfE[j] = qscales[cread[j]];   // flush scales g0
        asm volatile("s_waitcnt vmcnt(0)" ::: "memory");
        asm volatile("s_waitcnt lgkmcnt(0)" ::: "memory");
        __builtin_amdgcn_s_barrier();
    }

// body T (buf C): flush scales SFC (group T); stage tile T+1 with WC + zeros ZC
// (group T+1); prefetch words(T+2)->WL, zeros(T+2)->ZL, scales(T+1)->SFL.
// vmcnt(7): retires the 2 A-gloads, leaves [4 bw + 1 zw + 2 sc] in flight.
#define BODY(C, T, WC, ZC, SFC, WL, ZL, SFL)                                      \
  {                                                                               \
    const int tn1_ = ((T) + 1 < NT2) ? (T) + 1 : NT2 - 1;                         \
    const int tn2_ = ((T) + 2 < NT2) ? (T) + 2 : NT2 - 1;                         \
    float scur_[2];                                                               \
    _Pragma("unroll") for (int j = 0; j < 2; ++j)                                 \
      scur_[j] = ((float)SFC[j] - qszr[j]) * qssr[j];                             \
    const uint32_t kz_ = mk_kz(ZC);                                               \
    stage_B((C) ^ 1, WC, kz_);                                                    \
    SB0();                                                                        \
    stage_A((C) ^ 1, tn1_);                                                       \
    SB0();                                                                        \
    load_bw(tn2_, WL);                                                            \
    ZL = qzeros[(size_t)tn2_ * OPW + (ncol >> 3)];                                \
    _Pragma("unroll") for (int j = 0; j < 2; ++j)                                 \
      SFL[j] = qscales[(size_t)tn1_ * OUT_F + cread[j]];                          \
    SB0();                                                                        \
    compute(C, scur_);                                                            \
    asm volatile("s_waitcnt vmcnt(7)" ::: "memory");                              \
    asm volatile("s_waitcnt lgkmcnt(0)" ::: "memory");                            \
    __builtin_amdgcn_s_barrier();                                                 \
  }

    for (int t = 0; t < NT2; t += 2) {
        BODY(0, t,     wE, zwE, sfE, wO, zwO, sfO)
        BODY(1, t + 1, wO, zwO, sfO, wE, zwE, sfE)
    }
#undef BODY

    // -------- epilogue: C/D col=lane&15, row=(lane>>4)*4+reg; apply a[m] --------
    const int orow = m0 + wm * 64 + lo * 4;
    const int ocol = n0 + wn * 32 + lr;
    #pragma unroll
    for (int i = 0; i < 4; ++i)
        #pragma unroll
        for (int j = 0; j < 2; ++j)
            #pragma unroll
            for (int r = 0; r < 4; ++r) {
                const int rr = orow + i * 16 + r;
                out[(size_t)rr * OUT_F + ocol + j * 16] = aws[rr] * acc[i][j][r];
            }
}

// ---------------- fallback (no workspace): r10-style f16 kernel ----------------
static __device__ __forceinline__ f16x8 dequant8(uint32_t w, f16x2 sv, f16x2 zv) {
    uint32_t p0 = (w & 0x000F000Fu) | 0x64006400u;
    uint32_t p1 = ((w >> 4)  & 0x000F000Fu) | 0x64006400u;
    uint32_t p2 = ((w >> 8)  & 0x000F000Fu) | 0x64006400u;
    uint32_t p3 = ((w >> 12) & 0x000F000Fu) | 0x64006400u;
    f16x2 h0 = (__builtin_bit_cast(f16x2, p0) + zv) * sv;
    f16x2 h1 = (__builtin_bit_cast(f16x2, p1) + zv) * sv;
    f16x2 h2 = (__builtin_bit_cast(f16x2, p2) + zv) * sv;
    f16x2 h3 = (__builtin_bit_cast(f16x2, p3) + zv) * sv;
    f16x8 o;
    o[0] = h0[0]; o[1] = h0[1]; o[2] = h1[0]; o[3] = h1[1];
    o[4] = h2[0]; o[5] = h2[1]; o[6] = h3[0]; o[7] = h3[1];
    return o;
}

__global__ __launch_bounds__(512, 4) void qgemm_f16_fb(
    const float* __restrict__ x, const uint32_t* __restrict__ qweight,
    const uint32_t* __restrict__ qzeros, const int* __restrict__ qscales,
    const float* __restrict__ qscales_zeros, const float* __restrict__ qscales_scales,
    float* __restrict__ out)
{
    __shared__ __align__(16) f16 heap[2][(BM + BN) * 64];
    f16* const Ab0 = &heap[0][0];
    f16* const Ab1 = &heap[1][0];
    f16* const Bb0 = &heap[0][BM * 64];
    f16* const Bb1 = &heap[1][BM * 64];
    const int tid = threadIdx.x, lane = tid & 63, wid = tid >> 6;
    const int kg = wid >> 2, wm = (wid >> 1) & 1, wn = wid & 1;
    const int mt = blockIdx.x & 15, nt = blockIdx.x >> 4;
    const int m0 = mt * BM, n0 = nt * BN;
    const int colb = tid & 127, og2 = (tid >> 7) << 1, ncol = n0 + colb;
    const float ssv = qscales_scales[ncol], qzssv = qscales_zeros[ncol] * ssv;
    int bo[2];
    #pragma unroll
    for (int r = 0; r < 2; ++r) bo[r] = colb * 64 + ((og2 + r) ^ (colb & 7)) * 8;
    const uint32_t* bptr = qweight + (size_t)og2 * OUT_F + ncol;
    const int arow = tid >> 3, aoct = (tid & 7) ^ (arow & 7);
    const float* fsrc0 = x + (size_t)(m0 + arow) * IN_F + aoct * 8;
    const int aoff0 = tid * 8, aoff1 = (tid + 512) * 8;
    const int lr = lane & 15, lo = lane >> 4, koct = kg * 4 + lo;
    int offA[4], offB[4];
    #pragma unroll
    for (int f = 0; f < 4; ++f) {
        const int ra = wm * 64 + f * 16 + lr;
        offA[f] = ra * 64 + (koct ^ (ra & 7)) * 8;
        const int rb = wn * 64 + f * 16 + lr;
        offB[f] = rb * 64 + (koct ^ (rb & 7)) * 8;
    }
    f32x4 acc[4][4];
    #pragma unroll
    for (int i = 0; i < 4; ++i)
        #pragma unroll
        for (int j = 0; j < 4; ++j) { f32x4 z = {0,0,0,0}; acc[i][j] = z; }
    auto load_bw = [&](int t_, uint32_t* w) {
        const uint32_t* p = bptr + (size_t)t_ * 8 * OUT_F;
        w[0] = p[0]; w[1] = p[OUT_F];
    };
    auto mkc = [&](f16x2& sv_, f16x2& zv_, int sw_, uint32_t zw_) {
        const float sf = (float)sw_ * ssv - qzssv;
        const int z = (int)((zw_ >> ((ncol & 7) * 4)) & 0xFu);
        const f16 sh = (f16)sf, zh = (f16)(float)(-(1025 + z));
        sv_[0] = sh; sv_[1] = sh; zv_[0] = zh; zv_[1] = zh;
    };
    auto stage_B = [&](f16* Bb, const uint32_t* w, f16x2 sv_, f16x2 zv_) {
        *reinterpret_cast<f16x8*>(&Bb[bo[0]]) = dequant8(w[0], sv_, zv_);
        *reinterpret_cast<f16x8*>(&Bb[bo[1]]) = dequant8(w[1], sv_, zv_);
    };
    auto stage_A = [&](f16* Ab, int t_) {
        #pragma unroll
        for (int i = 0; i < 2; ++i) {
            const float* p = fsrc0 + (size_t)t_ * 64 + (size_t)(64 * i) * IN_F;
            const float4 v0 = *reinterpret_cast<const float4*>(p);
            const float4 v1 = *reinterpret_cast<const float4*>(p + 4);
            f16x8 v;
            v[0] = (f16)v0.x; v[1] = (f16)v1.x; v[2] = (f16)v0.y; v[3] = (f16)v1.y;
            v[4] = (f16)v0.z; v[5] = (f16)v1.z; v[6] = (f16)v0.w; v[7] = (f16)v1.w;
            *reinterpret_cast<f16x8*>(&Ab[i == 0 ? aoff0 : aoff1]) = v;
        }
    };
    auto compute = [&](const f16* Ab, const f16* Bb) {
        f16x8 af[4], bf[4];
        #pragma unroll
        for (int f = 0; f < 4; ++f) af[f] = *reinterpret_cast<const f16x8*>(&Ab[offA[f]]);
        #pragma unroll
        for (int f = 0; f < 4; ++f) bf[f] = *reinterpret_cast<const f16x8*>(&Bb[offB[f]]);
        #pragma unroll
        for (int i = 0; i < 4; ++i)
            #pragma unroll
            for (int j = 0; j < 4; ++j)
                acc[i][j] = __builtin_amdgcn_mfma_f32_16x16x32_f16(af[i], bf[j], acc[i][j], 0, 0, 0);
    };
    uint32_t wcur[2], wnxt[2];
    int swN; uint32_t zwN;
    f16x2 sv, zv, svN, zvN;
    {
        uint32_t w0[2];
        load_bw(0, w0);
        const int sw0 = qscales[ncol];
        const uint32_t zw0 = qzeros[ncol >> 3];
        stage_A(Ab0, 0);
        load_bw(1, wcur);
        swN = qscales[OUT_F + ncol]; zwN = qzeros[OPW + (ncol >> 3)];
        mkc(sv, zv, sw0, zw0);
        stage_B(Bb0, w0, sv, zv);
        asm volatile("s_waitcnt lgkmcnt(0)" ::: "memory");
        __builtin_amdgcn_s_barrier();
    }
    for (int t = 0; t < 64; t += 2) {
        mkc(svN, zvN, swN, zwN);
        stage_B(Bb1, wcur, sv, zv);
        stage_A(Ab1, t + 1);
        load_bw(t + 2 < 64 ? t + 2 : 63, wnxt);
        {
            const int g2 = (t >> 1) + 2 < NGROUP ? (t >> 1) + 2 : NGROUP - 1;
            swN = qscales[(size_t)g2 * OUT_F + ncol];
            zwN = qzeros[(size_t)g2 * OPW + (ncol >> 3)];
        }
        compute(Ab0, Bb0);
        asm volatile("s_waitcnt lgkmcnt(0)" ::: "memory");
        __builtin_amdgcn_s_barrier();
        sv = svN; zv = zvN;
        stage_B(Bb0, wnxt, sv, zv);
        stage_A(Ab0, t + 2 < 64 ? t + 2 : 63);
        load_bw(t + 3 < 64 ? t + 3 : 63, wcur);
        compute(Ab1, Bb1);
        asm volatile("s_waitcnt lgkmcnt(0)" ::: "memory");
        __builtin_amdgcn_s_barrier();
    }
    __syncthreads();
    f32x4* scratch = reinterpret_cast<f32x4*>(&heap[0][0]);
    const int wpos = wid & 3;
    #pragma unroll
    for (int hh = 0; hh < 2; ++hh) {
        if (kg == 1) {
            #pragma unroll
            for (int di = 0; di < 2; ++di)
                #pragma unroll
                for (int j = 0; j < 4; ++j)
                    scratch[wpos * 512 + (di * 4 + j) * 64 + lane] = acc[2 * hh + di][j];
        }
        __syncthreads();
        if (kg == 0) {
            #pragma unroll
            for (int di = 0; di < 2; ++di)
                #pragma unroll
                for (int j = 0; j < 4; ++j) {
                    const f32x4 p = scratch[wpos * 512 + (di * 4 + j) * 64 + lane];
                    acc[2 * hh + di][j].x += p.x; acc[2 * hh + di][j].y += p.y;
                    acc[2 * hh + di][j].z += p.z; acc[2 * hh + di][j].w += p.w;
                }
        }
        __syncthreads();
    }
    if (kg == 0) {
        const int orow = m0 + wm * 64 + lo * 4;
        const int ocol = n0 + wn * 64 + lr;
        #pragma unroll
        for (int i = 0; i < 4; ++i)
            #pragma unroll
            for (int j = 0; j < 4; ++j)
                #pragma unroll
                for (int r = 0; r < 4; ++r)
                    out[(size_t)(orow + i * 16 + r) * OUT_F + ocol + j * 16] = acc[i][j][r];
    }
}

extern "C" void kernel_launch(void* const* d_in, const int* in_sizes, int n_in,
                              void* d_out, int out_size, void* d_ws, size_t ws_size,
                              hipStream_t stream) {
    const float*    xp  = (const float*)d_in[0];
    const uint32_t* qw  = (const uint32_t*)d_in[1];
    const uint32_t* qz  = (const uint32_t*)d_in[2];
    const int*      qs  = (const int*)d_in[3];
    const float*    qsz = (const float*)d_in[4];
    const float*    qss = (const float*)d_in[5];
    // d_in[6] = g_idx: identity grouping (k/128), folded into the kernel.
    float* outp = (float*)d_out;

    const int grid = (TOKENS / BM) * (OUT_F / BN);   // 1376
    const size_t need = (size_t)TOKENS * IN_F + (size_t)TOKENS * 4;   // xi + a

    if (ws_size >= need) {
        char*  xi  = (char*)d_ws;
        float* aws = (float*)(xi + (size_t)TOKENS * IN_F);
        quant_x_kernel<<<TOKENS, 256, 0, stream>>>(xp, xi, aws);
        qgemm_i8_kernel<<<grid, 512, 0, stream>>>(xi, aws, qw, qz, qs, qsz, qss, outp);
    } else {
        qgemm_f16_fb<<<grid, 512, 0, stream>>>(xp, qw, qz, qs, qsz, qss, outp);
    }
}

// Round 18
// 179.691 us; speedup vs baseline: 8.9082x; 1.1767x over previous
//
#include <hip/hip_runtime.h>
#include <hip/hip_fp16.h>
#include <stdint.h>

#define IN_F   4096
#define OUT_F  11008
#define TOKENS 2048
#define BM 128
#define BN 64
#define BK 64
#define NT (IN_F / BK)     // 64 tiles; group = 2 tiles
#define NGROUP 32
#define OPW (OUT_F / 8)

typedef _Float16 f16;
typedef __attribute__((ext_vector_type(2))) _Float16 f16x2;
typedef __attribute__((ext_vector_type(8))) _Float16 f16x8;
typedef __attribute__((ext_vector_type(4))) float f32x4;
typedef __attribute__((ext_vector_type(4))) int   i32x4;

typedef __attribute__((address_space(3))) uint32_t lds_u32_t;
typedef const __attribute__((address_space(1))) uint32_t glb_u32_t;

#define SB0() __builtin_amdgcn_sched_barrier(0)

static __device__ __forceinline__ void gload_lds16(const void* g, void* l) {
    __builtin_amdgcn_global_load_lds((glb_u32_t*)g, (lds_u32_t*)l, 16, 0, 0);
}

// ---------------- pre-pass: per-row i8 quantization of x (r15-verified) --------
// xi byte order per 16-elem unit: {0,2,4,6, 1,3,5,7, 8,10,12,14, 9,11,13,15}
__global__ __launch_bounds__(256) void quant_x_kernel(const float* __restrict__ x,
                                                      char* __restrict__ xi,
                                                      float* __restrict__ aws) {
    __shared__ float red[4];
    const int row = blockIdx.x;
    const int tid = threadIdx.x;
    const float* xr = x + (size_t)row * IN_F + tid * 16;
    float v[16];
    #pragma unroll
    for (int p = 0; p < 4; ++p) {
        const float4 t = *reinterpret_cast<const float4*>(xr + p * 4);
        v[p * 4 + 0] = t.x; v[p * 4 + 1] = t.y; v[p * 4 + 2] = t.z; v[p * 4 + 3] = t.w;
    }
    float m = 0.f;
    #pragma unroll
    for (int p = 0; p < 16; ++p) m = fmaxf(m, fabsf(v[p]));
    #pragma unroll
    for (int off = 32; off > 0; off >>= 1) m = fmaxf(m, __shfl_xor(m, off));
    if ((tid & 63) == 0) red[tid >> 6] = m;
    __syncthreads();
    m = fmaxf(fmaxf(red[0], red[1]), fmaxf(red[2], red[3]));
    const float a   = m * (1.0f / 127.0f);
    const float inv = (m > 0.f) ? 127.0f / m : 0.f;
    if (tid == 0) aws[row] = a;
    const float MAGIC = 12582912.0f;   // 1.5*2^23: RNE int in low byte
    uint32_t b[16];
    #pragma unroll
    for (int p = 0; p < 16; ++p)
        b[p] = __builtin_bit_cast(uint32_t, fmaf(v[p], inv, MAGIC)) & 0xFFu;
    i32x4 d;
    d[0] = (int)(b[0] | (b[2] << 8) | (b[4]  << 16) | (b[6]  << 24));
    d[1] = (int)(b[1] | (b[3] << 8) | (b[5]  << 16) | (b[7]  << 24));
    d[2] = (int)(b[8] | (b[10] << 8) | (b[12] << 16) | (b[14] << 24));
    d[3] = (int)(b[9] | (b[11] << 8) | (b[13] << 16) | (b[15] << 24));
    *reinterpret_cast<i32x4*>(xi + (size_t)row * IN_F + tid * 16) = d;
}

// ---------------- i8 GEMM v3: 256 thr, 4 waves 64x32, BK=64, 24 KiB LDS --------
__global__ __launch_bounds__(256, 4) void qgemm_i8_kernel(
    const char*     __restrict__ xi,
    const float*    __restrict__ aws,
    const uint32_t* __restrict__ qweight,
    const uint32_t* __restrict__ qzeros,
    const int*      __restrict__ qscales,
    const float*    __restrict__ qscales_zeros,
    const float*    __restrict__ qscales_scales,
    float*          __restrict__ out)
{
    // i8 tiles; 16B unit (row, slot in [0,4)) holds k-unit slot^((row>>1)&3):
    // every aligned 8-lane b128 phase covers all 32 banks -> conflict-free.
    __shared__ __align__(16) char Ash[2][BM * BK];   // 2 x 8 KiB
    __shared__ __align__(16) char Bsh[2][BN * BK];   // 2 x 4 KiB  (24 KiB total)

    const int tid  = threadIdx.x;
    const int lane = tid & 63;
    const int wid  = tid >> 6;        // 0..3
    const int wm   = wid >> 1;        // 0..1  (M half: 64 rows)
    const int wn   = wid & 1;         // 0..1  (N half: 32 cols)

    const int mt = blockIdx.x & 15;
    const int nt = blockIdx.x >> 4;
    const int m0 = mt * BM;
    const int n0 = nt * BN;

    // ---- B staging: thread owns (col, unit h); one 16B unit = 2 packed words
    const int colb = tid & 63;
    const int h    = tid >> 6;        // 0..3 (== wid)
    const int ncol = n0 + colb;
    const int boff = colb * BK + (h ^ ((colb >> 1) & 3)) * 16;
    const uint32_t* bptr = qweight + (size_t)(2 * h) * OUT_F + ncol;

    // ---- A staging: 2 chunks/thread, linear dest, swizzled source
    const int arow = tid >> 2;                    // 0..63
    const int aunit = (tid & 3) ^ ((arow >> 1) & 3);
    const char* asrc0 = xi + (size_t)(m0 + arow) * IN_F + aunit * 16;   // +64*IN_F for chunk 1
    const int adst0 = tid * 16, adst1 = (tid + 256) * 16;

    // ---- fragment offsets (K=64: one i32x4 per 16-row frag)
    const int lr = lane & 15;
    const int lo = lane >> 4;         // 0..3 k-unit
    int aoffr[4], boffr[2];
    #pragma unroll
    for (int f = 0; f < 4; ++f) {
        const int ra = wm * 64 + f * 16 + lr;
        aoffr[f] = ra * BK + ((lo ^ ((ra >> 1) & 3))) * 16;
    }
    #pragma unroll
    for (int j = 0; j < 2; ++j) {
        const int rb = wn * 32 + j * 16 + lr;
        boffr[j] = rb * BK + ((lo ^ ((rb >> 1) & 3))) * 16;
    }
    const int cread0 = n0 + wn * 32 + lr;
    const int cread1 = cread0 + 16;
    float qszr[2], qssr[2];
    qszr[0] = qscales_zeros[cread0]; qssr[0] = qscales_scales[cread0];
    qszr[1] = qscales_zeros[cread1]; qssr[1] = qscales_scales[cread1];

    f32x4 acc[4][2];
    #pragma unroll
    for (int i = 0; i < 4; ++i)
        #pragma unroll
        for (int j = 0; j < 2; ++j) {
            f32x4 z = {0.f, 0.f, 0.f, 0.f};
            acc[i][j] = z;
        }
    i32x4 D[4][2];   // chained across the 2-tile group

    auto load_bw = [&](int t_, uint32_t* w) {
        const uint32_t* p = bptr + (size_t)t_ * 8 * OUT_F;
        w[0] = p[0];
        w[1] = p[OUT_F];
    };
    auto mk_kz = [&](uint32_t zw_) -> uint32_t {
        const uint32_t znib = (zw_ >> ((ncol & 7) * 4)) & 0xFu;
        return (127u - znib) * 0x01010101u;   // per-byte +(128-(z+1)), then ^0x80
    };
    auto stage_B = [&](int buf, const uint32_t* w, uint32_t kz) {
        i32x4 d;
        d[0] = (int)((((w[0]      ) & 0x0F0F0F0Fu) + kz) ^ 0x80808080u);
        d[1] = (int)((((w[0] >> 4 ) & 0x0F0F0F0Fu) + kz) ^ 0x80808080u);
        d[2] = (int)((((w[1]      ) & 0x0F0F0F0Fu) + kz) ^ 0x80808080u);
        d[3] = (int)((((w[1] >> 4 ) & 0x0F0F0F0Fu) + kz) ^ 0x80808080u);
        *reinterpret_cast<i32x4*>(&Bsh[buf][boff]) = d;
    };
    auto stage_A = [&](int buf, int t_) {
        gload_lds16(asrc0 + (size_t)t_ * BK, &Ash[buf][adst0]);
        gload_lds16(asrc0 + (size_t)t_ * BK + (size_t)64 * IN_F, &Ash[buf][adst1]);
    };

    uint32_t wE[2], wO[2];
    uint32_t zwE, zwO;
    int sfE[2], sfO[2];

    // -------- prologue: stage tile 0; prime 1-tile-lead prefetches (set E) ------
    {
        uint32_t w00[2];
        load_bw(0, w00);
        const uint32_t zw0 = qzeros[ncol >> 3];          // group 0
        stage_A(0, 0);
        stage_B(0, w00, mk_kz(zw0));
        load_bw(1, wE);                                   // words tile 1
        zwE = qzeros[ncol >> 3];                          // zeros group (0+1)>>1 = 0
        sfE[0] = qscales[cread0];                         // scales group 0
        sfE[1] = qscales[cread1];
        asm volatile("s_waitcnt vmcnt(0)" ::: "memory");
        asm volatile("s_waitcnt lgkmcnt(0)" ::: "memory");
        __builtin_amdgcn_s_barrier();
    }

// BODY tile T (buf C): stage tile T+1 into C^1 (B from WC + zeros ZC); issue
// [2 A-gloads][2 bw][1 zw][2 sf] (1-tile lead, SB0-pinned order); compute 8 MFMA
// (even: D fresh; odd: chain + f32 flush with SFC); vmcnt(5) retires the 2
// A-gloads only -- the 5 register loads stay in flight across the barrier.
#define BODY(C, T, WC, ZC, SFC, WL, ZL, SFL, ODD)                                 \
  {                                                                               \
    const int tn1_ = ((T) + 1 < NT) ? (T) + 1 : NT - 1;                           \
    const int tn2_ = ((T) + 2 < NT) ? (T) + 2 : NT - 1;                           \
    const int gz_  = ((T) + 2) >> 1 < NGROUP ? ((T) + 2) >> 1 : NGROUP - 1;       \
    const int gs_  = ((T) + 1) >> 1 < NGROUP ? ((T) + 1) >> 1 : NGROUP - 1;       \
    stage_B((C) ^ 1, WC, mk_kz(ZC));                                              \
    stage_A((C) ^ 1, tn1_);                                                       \
    SB0();                                                                        \
    load_bw(tn2_, WL);                                                            \
    ZL = qzeros[(size_t)gz_ * OPW + (ncol >> 3)];                                 \
    SFL[0] = qscales[(size_t)gs_ * OUT_F + cread0];                               \
    SFL[1] = qscales[(size_t)gs_ * OUT_F + cread1];                               \
    SB0();                                                                        \
    {                                                                             \
      i32x4 af[4], bf[2];                                                         \
      _Pragma("unroll") for (int f = 0; f < 4; ++f)                               \
        af[f] = *reinterpret_cast<const i32x4*>(&Ash[C][aoffr[f]]);               \
      _Pragma("unroll") for (int j = 0; j < 2; ++j)                               \
        bf[j] = *reinterpret_cast<const i32x4*>(&Bsh[C][boffr[j]]);               \
      __builtin_amdgcn_s_setprio(1);                                              \
      if (ODD) {                                                                  \
        _Pragma("unroll") for (int i = 0; i < 4; ++i)                             \
          _Pragma("unroll") for (int j = 0; j < 2; ++j)                           \
            D[i][j] = __builtin_amdgcn_mfma_i32_16x16x64_i8(af[i], bf[j],         \
                                                            D[i][j], 0, 0, 0);   \
      } else {                                                                    \
        _Pragma("unroll") for (int i = 0; i < 4; ++i)                             \
          _Pragma("unroll") for (int j = 0; j < 2; ++j) {                         \
            i32x4 z0_ = {0, 0, 0, 0};                                             \
            D[i][j] = __builtin_amdgcn_mfma_i32_16x16x64_i8(af[i], bf[j],         \
                                                            z0_, 0, 0, 0);       \
          }                                                                       \
      }                                                                           \
      __builtin_amdgcn_s_setprio(0);                                              \
    }                                                                             \
    if (ODD) {                                                                    \
      float scur_[2];                                                             \
      _Pragma("unroll") for (int j = 0; j < 2; ++j)                               \
        scur_[j] = ((float)SFC[j] - qszr[j]) * qssr[j];                           \
      _Pragma("unroll") for (int i = 0; i < 4; ++i)                               \
        _Pragma("unroll") for (int j = 0; j < 2; ++j) {                           \
          acc[i][j].x += scur_[j] * (float)D[i][j][0];                            \
          acc[i][j].y += scur_[j] * (float)D[i][j][1];                            \
          acc[i][j].z += scur_[j] * (float)D[i][j][2];                            \
          acc[i][j].w += scur_[j] * (float)D[i][j][3];                            \
        }                                                                         \
    }                                                                             \
    asm volatile("s_waitcnt vmcnt(5)" ::: "memory");                              \
    asm volatile("s_waitcnt lgkmcnt(0)" ::: "memory");                            \
    __builtin_amdgcn_s_barrier();                                                 \
  }

    for (int t = 0; t < NT; t += 2) {
        BODY(0, t,     wE, zwE, sfE, wO, zwO, sfO, false)
        BODY(1, t + 1, wO, zwO, sfO, wE, zwE, sfE, true)
    }
#undef BODY

    // -------- epilogue: C/D col=lane&15, row=(lane>>4)*4+reg; apply a[m] --------
    const int orow = m0 + wm * 64 + lo * 4;
    const int ocol = n0 + wn * 32 + lr;
    #pragma unroll
    for (int i = 0; i < 4; ++i)
        #pragma unroll
        for (int j = 0; j < 2; ++j)
            #pragma unroll
            for (int r = 0; r < 4; ++r) {
                const int rr = orow + i * 16 + r;
                out[(size_t)rr * OUT_F + ocol + j * 16] = aws[rr] * acc[i][j][r];
            }
}

// ---------------- fallback (no workspace): r10-style f16 kernel (128x128x64) ----
static __device__ __forceinline__ f16x8 dequant8(uint32_t w, f16x2 sv, f16x2 zv) {
    uint32_t p0 = (w & 0x000F000Fu) | 0x64006400u;
    uint32_t p1 = ((w >> 4)  & 0x000F000Fu) | 0x64006400u;
    uint32_t p2 = ((w >> 8)  & 0x000F000Fu) | 0x64006400u;
    uint32_t p3 = ((w >> 12) & 0x000F000Fu) | 0x64006400u;
    f16x2 h0 = (__builtin_bit_cast(f16x2, p0) + zv) * sv;
    f16x2 h1 = (__builtin_bit_cast(f16x2, p1) + zv) * sv;
    f16x2 h2 = (__builtin_bit_cast(f16x2, p2) + zv) * sv;
    f16x2 h3 = (__builtin_bit_cast(f16x2, p3) + zv) * sv;
    f16x8 o;
    o[0] = h0[0]; o[1] = h0[1]; o[2] = h1[0]; o[3] = h1[1];
    o[4] = h2[0]; o[5] = h2[1]; o[6] = h3[0]; o[7] = h3[1];
    return o;
}

__global__ __launch_bounds__(512, 4) void qgemm_f16_fb(
    const float* __restrict__ x, const uint32_t* __restrict__ qweight,
    const uint32_t* __restrict__ qzeros, const int* __restrict__ qscales,
    const float* __restrict__ qscales_zeros, const float* __restrict__ qscales_scales,
    float* __restrict__ out)
{
    __shared__ __align__(16) f16 heap[2][256 * 64];
    f16* const Ab0 = &heap[0][0];
    f16* const Ab1 = &heap[1][0];
    f16* const Bb0 = &heap[0][128 * 64];
    f16* const Bb1 = &heap[1][128 * 64];
    const int tid = threadIdx.x, lane = tid & 63, wid = tid >> 6;
    const int kg = wid >> 2, wm = (wid >> 1) & 1, wn = wid & 1;
    const int mt = blockIdx.x & 15, nt = blockIdx.x >> 4;
    const int m0 = mt * 128, n0 = nt * 128;
    const int colb = tid & 127, og2 = (tid >> 7) << 1, ncol = n0 + colb;
    const float ssv = qscales_scales[ncol], qzssv = qscales_zeros[ncol] * ssv;
    int bo[2];
    #pragma unroll
    for (int r = 0; r < 2; ++r) bo[r] = colb * 64 + ((og2 + r) ^ (colb & 7)) * 8;
    const uint32_t* bptr = qweight + (size_t)og2 * OUT_F + ncol;
    const int arow = tid >> 3, aoct = (tid & 7) ^ (arow & 7);
    const float* fsrc0 = x + (size_t)(m0 + arow) * IN_F + aoct * 8;
    const int aoff0 = tid * 8, aoff1 = (tid + 512) * 8;
    const int lr = lane & 15, lo = lane >> 4, koct = kg * 4 + lo;
    int offA[4], offB[4];
    #pragma unroll
    for (int f = 0; f < 4; ++f) {
        const int ra = wm * 64 + f * 16 + lr;
        offA[f] = ra * 64 + (koct ^ (ra & 7)) * 8;
        const int rb = wn * 64 + f * 16 + lr;
        offB[f] = rb * 64 + (koct ^ (rb & 7)) * 8;
    }
    f32x4 acc[4][4];
    #pragma unroll
    for (int i = 0; i < 4; ++i)
        #pragma unroll
        for (int j = 0; j < 4; ++j) { f32x4 z = {0,0,0,0}; acc[i][j] = z; }
    auto load_bw = [&](int t_, uint32_t* w) {
        const uint32_t* p = bptr + (size_t)t_ * 8 * OUT_F;
        w[0] = p[0]; w[1] = p[OUT_F];
    };
    auto mkc = [&](f16x2& sv_, f16x2& zv_, int sw_, uint32_t zw_) {
        const float sf = (float)sw_ * ssv - qzssv;
        const int z = (int)((zw_ >> ((ncol & 7) * 4)) & 0xFu);
        const f16 sh = (f16)sf, zh = (f16)(float)(-(1025 + z));
        sv_[0] = sh; sv_[1] = sh; zv_[0] = zh; zv_[1] = zh;
    };
    auto stage_B = [&](f16* Bb, const uint32_t* w, f16x2 sv_, f16x2 zv_) {
        *reinterpret_cast<f16x8*>(&Bb[bo[0]]) = dequant8(w[0], sv_, zv_);
        *reinterpret_cast<f16x8*>(&Bb[bo[1]]) = dequant8(w[1], sv_, zv_);
    };
    auto stage_A = [&](f16* Ab, int t_) {
        #pragma unroll
        for (int i = 0; i < 2; ++i) {
            const float* p = fsrc0 + (size_t)t_ * 64 + (size_t)(64 * i) * IN_F;
            const float4 v0 = *reinterpret_cast<const float4*>(p);
            const float4 v1 = *reinterpret_cast<const float4*>(p + 4);
            f16x8 v;
            v[0] = (f16)v0.x; v[1] = (f16)v1.x; v[2] = (f16)v0.y; v[3] = (f16)v1.y;
            v[4] = (f16)v0.z; v[5] = (f16)v1.z; v[6] = (f16)v0.w; v[7] = (f16)v1.w;
            *reinterpret_cast<f16x8*>(&Ab[i == 0 ? aoff0 : aoff1]) = v;
        }
    };
    auto compute = [&](const f16* Ab, const f16* Bb) {
        f16x8 af[4], bf[4];
        #pragma unroll
        for (int f = 0; f < 4; ++f) af[f] = *reinterpret_cast<const f16x8*>(&Ab[offA[f]]);
        #pragma unroll
        for (int f = 0; f < 4; ++f) bf[f] = *reinterpret_cast<const f16x8*>(&Bb[offB[f]]);
        #pragma unroll
        for (int i = 0; i < 4; ++i)
            #pragma unroll
            for (int j = 0; j < 4; ++j)
                acc[i][j] = __builtin_amdgcn_mfma_f32_16x16x32_f16(af[i], bf[j], acc[i][j], 0, 0, 0);
    };
    uint32_t wcur[2], wnxt[2];
    int swN; uint32_t zwN;
    f16x2 sv, zv, svN, zvN;
    {
        uint32_t w0[2];
        load_bw(0, w0);
        const int sw0 = qscales[ncol];
        const uint32_t zw0 = qzeros[ncol >> 3];
        stage_A(Ab0, 0);
        load_bw(1, wcur);
        swN = qscales[OUT_F + ncol]; zwN = qzeros[OPW + (ncol >> 3)];
        mkc(sv, zv, sw0, zw0);
        stage_B(Bb0, w0, sv, zv);
        asm volatile("s_waitcnt lgkmcnt(0)" ::: "memory");
        __builtin_amdgcn_s_barrier();
    }
    for (int t = 0; t < 64; t += 2) {
        mkc(svN, zvN, swN, zwN);
        stage_B(Bb1, wcur, sv, zv);
        stage_A(Ab1, t + 1);
        load_bw(t + 2 < 64 ? t + 2 : 63, wnxt);
        {
            const int g2 = (t >> 1) + 2 < NGROUP ? (t >> 1) + 2 : NGROUP - 1;
            swN = qscales[(size_t)g2 * OUT_F + ncol];
            zwN = qzeros[(size_t)g2 * OPW + (ncol >> 3)];
        }
        compute(Ab0, Bb0);
        asm volatile("s_waitcnt lgkmcnt(0)" ::: "memory");
        __builtin_amdgcn_s_barrier();
        sv = svN; zv = zvN;
        stage_B(Bb0, wnxt, sv, zv);
        stage_A(Ab0, t + 2 < 64 ? t + 2 : 63);
        load_bw(t + 3 < 64 ? t + 3 : 63, wcur);
        compute(Ab1, Bb1);
        asm volatile("s_waitcnt lgkmcnt(0)" ::: "memory");
        __builtin_amdgcn_s_barrier();
    }
    __syncthreads();
    f32x4* scratch = reinterpret_cast<f32x4*>(&heap[0][0]);
    const int wpos = wid & 3;
    #pragma unroll
    for (int hh = 0; hh < 2; ++hh) {
        if (kg == 1) {
            #pragma unroll
            for (int di = 0; di < 2; ++di)
                #pragma unroll
                for (int j = 0; j < 4; ++j)
                    scratch[wpos * 512 + (di * 4 + j) * 64 + lane] = acc[2 * hh + di][j];
        }
        __syncthreads();
        if (kg == 0) {
            #pragma unroll
            for (int di = 0; di < 2; ++di)
                #pragma unroll
                for (int j = 0; j < 4; ++j) {
                    const f32x4 p = scratch[wpos * 512 + (di * 4 + j) * 64 + lane];
                    acc[2 * hh + di][j].x += p.x; acc[2 * hh + di][j].y += p.y;
                    acc[2 * hh + di][j].z += p.z; acc[2 * hh + di][j].w += p.w;
                }
        }
        __syncthreads();
    }
    if (kg == 0) {
        const int orow = m0 + wm * 64 + lo * 4;
        const int ocol = n0 + wn * 64 + lr;
        #pragma unroll
        for (int i = 0; i < 4; ++i)
            #pragma unroll
            for (int j = 0; j < 4; ++j)
                #pragma unroll
                for (int r = 0; r < 4; ++r)
                    out[(size_t)(orow + i * 16 + r) * OUT_F + ocol + j * 16] = acc[i][j][r];
    }
}

extern "C" void kernel_launch(void* const* d_in, const int* in_sizes, int n_in,
                              void* d_out, int out_size, void* d_ws, size_t ws_size,
                              hipStream_t stream) {
    const float*    xp  = (const float*)d_in[0];
    const uint32_t* qw  = (const uint32_t*)d_in[1];
    const uint32_t* qz  = (const uint32_t*)d_in[2];
    const int*      qs  = (const int*)d_in[3];
    const float*    qsz = (const float*)d_in[4];
    const float*    qss = (const float*)d_in[5];
    // d_in[6] = g_idx: identity grouping (k/128), folded into the kernel.
    float* outp = (float*)d_out;

    const size_t need = (size_t)TOKENS * IN_F + (size_t)TOKENS * 4;   // xi + a

    if (ws_size >= need) {
        char*  xi  = (char*)d_ws;
        float* aws = (float*)(xi + (size_t)TOKENS * IN_F);
        quant_x_kernel<<<TOKENS, 256, 0, stream>>>(xp, xi, aws);
        const int grid = (TOKENS / BM) * (OUT_F / BN);   // 16 * 172 = 2752
        qgemm_i8_kernel<<<grid, 256, 0, stream>>>(xi, aws, qw, qz, qs, qsz, qss, outp);
    } else {
        const int gridf = (TOKENS / 128) * (OUT_F / 128); // 1376
        qgemm_f16_fb<<<gridf, 512, 0, stream>>>(xp, qw, qz, qs, qsz, qss, outp);
    }
}